// Round 5
// baseline (729.308 us; speedup 1.0000x reference)
//
#include <hip/hip_runtime.h>
#include <hip/hip_cooperative_groups.h>

namespace cg = cooperative_groups;

#define HW_ELEMS (512 * 512)             // elements per (n,c) channel
#define HW4      (HW_ELEMS / 4)          // 65536 float4 per channel
#define NC 192
#define THREADS 256
#define FX4_PER_THREAD 16                // 64 VGPRs of data per thread
#define SLICE_FX4 (THREADS * FX4_PER_THREAD)   // 4096 fx4 = 64 KB per block-slice
#define SLICES_PER_CH (HW4 / SLICE_FX4)        // 16
#define TOTAL_SLICES (NC * SLICES_PER_CH)      // 3072
#define GRID 512                               // 2 blocks/CU co-residency req.
#define PHASES (TOTAL_SLICES / GRID)           // 6
#define EPS 1e-8f

typedef float fx4 __attribute__((ext_vector_type(4)));

// Fused single-pass instance norm: each slice lives in registers across the
// stats -> grid.sync -> normalize sequence, so the input is read from HBM
// exactly once. 6 phases of 512 slices; channel boundaries (16 slices) never
// straddle a phase (512 % 16 == 0), and phase p+1 writes partial slots
// strictly above everything phase p reads -> no cross-phase race.
__global__ __launch_bounds__(THREADS) void instnorm_fused(
    const float* __restrict__ in, float* __restrict__ out,
    float2* __restrict__ partials)
{
    cg::grid_group grid = cg::this_grid();
    const int t = threadIdx.x;

    for (int p = 0; p < PHASES; ++p) {
        const int s = p * GRID + blockIdx.x;           // slice index
        const int c = s >> 4;                          // channel (16 slices/ch)
        const size_t base = (size_t)c * HW4
                          + (size_t)(s & (SLICES_PER_CH - 1)) * SLICE_FX4;

        // ---- pass 1: load slice into registers, accumulate sum/sumsq ----
        fx4 v[FX4_PER_THREAD];
        float sum = 0.f, sq = 0.f;
#pragma unroll
        for (int k = 0; k < FX4_PER_THREAD; ++k) {
            v[k] = reinterpret_cast<const fx4*>(in)[base + t + k * THREADS];
            sum += (v[k].x + v[k].y) + (v[k].z + v[k].w);
            sq  += v[k].x * v[k].x + v[k].y * v[k].y
                 + v[k].z * v[k].z + v[k].w * v[k].w;
        }

        // wave (64-lane) reduction
#pragma unroll
        for (int off = 32; off > 0; off >>= 1) {
            sum += __shfl_down(sum, off, 64);
            sq  += __shfl_down(sq,  off, 64);
        }
        __shared__ float s_sum[4];
        __shared__ float s_sq[4];
        if ((t & 63) == 0) { s_sum[t >> 6] = sum; s_sq[t >> 6] = sq; }
        __syncthreads();
        if (t == 0) {
            partials[s] = make_float2(s_sum[0] + s_sum[1] + s_sum[2] + s_sum[3],
                                      s_sq[0]  + s_sq[1]  + s_sq[2]  + s_sq[3]);
        }
        __threadfence();          // publish partial device-wide
        grid.sync();

        // ---- combine channel partials (fixed order, deterministic) ----
        float S = 0.f, Q = 0.f;
#pragma unroll
        for (int i = 0; i < SLICES_PER_CH; ++i) {
            float2 pq = partials[c * SLICES_PER_CH + i];
            S += pq.x; Q += pq.y;
        }
        const float n = (float)HW_ELEMS;
        float mean = S / n;
        float var  = (Q - S * S / n) / (n - 1.0f);    // unbiased (ddof=1)
        if (var < 0.f) var = 0.f;
        float rstd = 1.0f / (sqrtf(var) + EPS);

        // ---- pass 2: normalize register-resident slice, stream out ----
#pragma unroll
        for (int k = 0; k < FX4_PER_THREAD; ++k) {
            fx4 r;
            r.x = (v[k].x - mean) * rstd;
            r.y = (v[k].y - mean) * rstd;
            r.z = (v[k].z - mean) * rstd;
            r.w = (v[k].w - mean) * rstd;
            __builtin_nontemporal_store(
                r, reinterpret_cast<fx4*>(out) + base + t + k * THREADS);
        }
    }
}

// ---------- fallback path (two-kernel, Round-3 proven) ----------
#define BPC 8
__global__ __launch_bounds__(256) void instnorm_partial(
    const float* __restrict__ in, float2* __restrict__ partials)
{
    const int c = blockIdx.x >> 3;
    const int b = blockIdx.x & (BPC - 1);
    const fx4* p = reinterpret_cast<const fx4*>(in)
                 + (size_t)c * HW4 + (size_t)b * (HW4 / BPC);
    const int t = threadIdx.x;
    float sum = 0.f, sumsq = 0.f;
#pragma unroll
    for (int k = 0; k < HW4 / BPC / 256; ++k) {
        fx4 v = p[t + k * 256];
        sum   += (v.x + v.y) + (v.z + v.w);
        sumsq += (v.x * v.x + v.y * v.y) + (v.z * v.z + v.w * v.w);
    }
#pragma unroll
    for (int off = 32; off > 0; off >>= 1) {
        sum   += __shfl_down(sum, off, 64);
        sumsq += __shfl_down(sumsq, off, 64);
    }
    __shared__ float s_sum[4];
    __shared__ float s_sq[4];
    if ((t & 63) == 0) { s_sum[t >> 6] = sum; s_sq[t >> 6] = sumsq; }
    __syncthreads();
    if (t == 0) {
        partials[blockIdx.x] = make_float2(s_sum[0] + s_sum[1] + s_sum[2] + s_sum[3],
                                           s_sq[0] + s_sq[1] + s_sq[2] + s_sq[3]);
    }
}

__global__ __launch_bounds__(256) void instnorm_apply(
    const float* __restrict__ in, float* __restrict__ out,
    const float2* __restrict__ partials)
{
    const int c = blockIdx.x >> 8;
    float S = 0.f, Q = 0.f;
#pragma unroll
    for (int b = 0; b < BPC; ++b) {
        float2 pq = partials[c * BPC + b];
        S += pq.x; Q += pq.y;
    }
    const float n = (float)HW_ELEMS;
    float mean = S / n;
    float var  = (Q - S * S / n) / (n - 1.0f);
    if (var < 0.f) var = 0.f;
    float rstd = 1.0f / (sqrtf(var) + EPS);

    const size_t i4 = (size_t)blockIdx.x * 256 + threadIdx.x;
    fx4 v = reinterpret_cast<const fx4*>(in)[i4];
    fx4 r;
    r.x = (v.x - mean) * rstd;
    r.y = (v.y - mean) * rstd;
    r.z = (v.z - mean) * rstd;
    r.w = (v.w - mean) * rstd;
    __builtin_nontemporal_store(r, reinterpret_cast<fx4*>(out) + i4);
}

extern "C" void kernel_launch(void* const* d_in, const int* in_sizes, int n_in,
                              void* d_out, int out_size, void* d_ws, size_t ws_size,
                              hipStream_t stream) {
    const float* in = (const float*)d_in[0];
    float* out = (float*)d_out;
    float2* partials = (float2*)d_ws;    // TOTAL_SLICES * 8 B = 24 KiB

    void* args[] = { (void*)&in, (void*)&out, (void*)&partials };
    hipError_t rc = hipLaunchCooperativeKernel((const void*)instnorm_fused,
                                               dim3(GRID), dim3(THREADS),
                                               args, 0, stream);
    if (rc != hipSuccess) {
        // Cooperative launch refused (co-residency / capture limitation):
        // run the proven two-kernel path instead.
        instnorm_partial<<<NC * BPC, 256, 0, stream>>>(in, partials);
        const size_t total4 = (size_t)NC * HW4;
        instnorm_apply<<<(int)(total4 / 256), 256, 0, stream>>>(in, out, partials);
    }
}

// Round 6
// 194.083 us; speedup vs baseline: 3.7577x; 3.7577x over previous
//
#include <hip/hip_runtime.h>

#define HW_ELEMS (512 * 512)             // elements per (n,c) channel
#define HW4      (HW_ELEMS / 4)          // 65536 fx4 per channel
#define NC 192
#define THREADS 256
#define BPC 8                            // blocks per channel
#define SLICE4 (HW4 / BPC)               // 8192 fx4 per block slice (128 KB)
#define NBLK (NC * BPC)                  // 1536 blocks (6/CU -> co-resident)
#define EPS 1e-8f

typedef float fx4 __attribute__((ext_vector_type(4)));

// Fused instance norm, no grid.sync: per-channel semaphore among the 8
// blocks that own the channel. Cooperative launch guarantees all 1536
// blocks are co-resident, so the spin is bounded (~us: siblings progress
// in lockstep). The re-read of the 128 KB slice happens ~us after the
// first read -> L2/L3 hit, so HBM traffic ~= 201 MB read + 201 MB write.
__global__ __launch_bounds__(THREADS, 6) void instnorm_coop(
    const float* __restrict__ in, float* __restrict__ out,
    float* __restrict__ psum, float* __restrict__ psq,
    unsigned* __restrict__ sem)
{
    const int s = blockIdx.x;
    const int c = s >> 3;                 // channel
    const int b = s & (BPC - 1);          // slice within channel
    const size_t base = (size_t)c * HW4 + (size_t)b * SLICE4;
    const fx4* p = reinterpret_cast<const fx4*>(in) + base;
    const int t = threadIdx.x;

    // ---- pass 1: slice stats ----
    float sum = 0.f, sq = 0.f;
#pragma unroll 4
    for (int k = 0; k < SLICE4 / THREADS; ++k) {      // 32 iters
        fx4 v = p[t + k * THREADS];
        sum += (v.x + v.y) + (v.z + v.w);
        sq  += v.x * v.x + v.y * v.y + v.z * v.z + v.w * v.w;
    }
#pragma unroll
    for (int off = 32; off > 0; off >>= 1) {
        sum += __shfl_down(sum, off, 64);
        sq  += __shfl_down(sq,  off, 64);
    }
    __shared__ float s_sum[4];
    __shared__ float s_sq[4];
    if ((t & 63) == 0) { s_sum[t >> 6] = sum; s_sq[t >> 6] = sq; }
    __syncthreads();

    // ---- publish partial, bump channel counter (device scope) ----
    if (t == 0) {
        float S = s_sum[0] + s_sum[1] + s_sum[2] + s_sum[3];
        float Q = s_sq[0]  + s_sq[1]  + s_sq[2]  + s_sq[3];
        __hip_atomic_store(&psum[s], S, __ATOMIC_RELAXED, __HIP_MEMORY_SCOPE_AGENT);
        __hip_atomic_store(&psq[s],  Q, __ATOMIC_RELAXED, __HIP_MEMORY_SCOPE_AGENT);
        __hip_atomic_fetch_add(&sem[c], 1u, __ATOMIC_RELEASE, __HIP_MEMORY_SCOPE_AGENT);
        // spin until all 8 slices of this channel have published
        while (__hip_atomic_load(&sem[c], __ATOMIC_ACQUIRE, __HIP_MEMORY_SCOPE_AGENT) < BPC)
            __builtin_amdgcn_s_sleep(1);
    }
    __syncthreads();

    // ---- combine channel partials (fixed order -> deterministic) ----
    float S = 0.f, Q = 0.f;
#pragma unroll
    for (int i = 0; i < BPC; ++i) {
        S += __hip_atomic_load(&psum[c * BPC + i], __ATOMIC_RELAXED, __HIP_MEMORY_SCOPE_AGENT);
        Q += __hip_atomic_load(&psq[c * BPC + i],  __ATOMIC_RELAXED, __HIP_MEMORY_SCOPE_AGENT);
    }
    const float n = (float)HW_ELEMS;
    float mean = S / n;
    float var  = (Q - S * S / n) / (n - 1.0f);        // unbiased (ddof=1)
    if (var < 0.f) var = 0.f;
    float rstd = 1.0f / (sqrtf(var) + EPS);

    // ---- pass 2: re-read slice (L2/L3-hot, ~us old), normalize, store ----
#pragma unroll 4
    for (int k = 0; k < SLICE4 / THREADS; ++k) {
        fx4 v = p[t + k * THREADS];
        fx4 r;
        r.x = (v.x - mean) * rstd;
        r.y = (v.y - mean) * rstd;
        r.z = (v.z - mean) * rstd;
        r.w = (v.w - mean) * rstd;
        __builtin_nontemporal_store(
            r, reinterpret_cast<fx4*>(out) + base + t + k * THREADS);
    }
}

// ---------- fallback path (two-kernel, reversed apply order) ----------
__global__ __launch_bounds__(256) void instnorm_partial(
    const float* __restrict__ in, float* __restrict__ psum, float* __restrict__ psq)
{
    const int c = blockIdx.x >> 3;
    const int b = blockIdx.x & (BPC - 1);
    const fx4* p = reinterpret_cast<const fx4*>(in)
                 + (size_t)c * HW4 + (size_t)b * SLICE4;
    const int t = threadIdx.x;
    float sum = 0.f, sq = 0.f;
#pragma unroll 4
    for (int k = 0; k < SLICE4 / 256; ++k) {
        fx4 v = p[t + k * 256];
        sum += (v.x + v.y) + (v.z + v.w);
        sq  += v.x * v.x + v.y * v.y + v.z * v.z + v.w * v.w;
    }
#pragma unroll
    for (int off = 32; off > 0; off >>= 1) {
        sum += __shfl_down(sum, off, 64);
        sq  += __shfl_down(sq,  off, 64);
    }
    __shared__ float s_sum[4];
    __shared__ float s_sq[4];
    if ((t & 63) == 0) { s_sum[t >> 6] = sum; s_sq[t >> 6] = sq; }
    __syncthreads();
    if (t == 0) {
        psum[blockIdx.x] = s_sum[0] + s_sum[1] + s_sum[2] + s_sum[3];
        psq[blockIdx.x]  = s_sq[0] + s_sq[1] + s_sq[2] + s_sq[3];
    }
}

__global__ __launch_bounds__(256) void instnorm_apply_rev(
    const float* __restrict__ in, float* __restrict__ out,
    const float* __restrict__ psum, const float* __restrict__ psq)
{
    // reversed mapping: late blocks (launched first) handle data read most
    // recently by the stats pass -> consume MRU lines before write-stream
    // evictions (LRU) reach them.
    const int nblk = (int)((size_t)NC * HW4 / 256);
    const int rb = nblk - 1 - blockIdx.x;
    const int c = rb >> 8;
    float S = 0.f, Q = 0.f;
#pragma unroll
    for (int i = 0; i < BPC; ++i) { S += psum[c * BPC + i]; Q += psq[c * BPC + i]; }
    const float n = (float)HW_ELEMS;
    float mean = S / n;
    float var  = (Q - S * S / n) / (n - 1.0f);
    if (var < 0.f) var = 0.f;
    float rstd = 1.0f / (sqrtf(var) + EPS);

    const size_t i4 = (size_t)rb * 256 + threadIdx.x;
    fx4 v = reinterpret_cast<const fx4*>(in)[i4];
    fx4 r;
    r.x = (v.x - mean) * rstd;
    r.y = (v.y - mean) * rstd;
    r.z = (v.z - mean) * rstd;
    r.w = (v.w - mean) * rstd;
    __builtin_nontemporal_store(r, reinterpret_cast<fx4*>(out) + i4);
}

extern "C" void kernel_launch(void* const* d_in, const int* in_sizes, int n_in,
                              void* d_out, int out_size, void* d_ws, size_t ws_size,
                              hipStream_t stream) {
    const float* in = (const float*)d_in[0];
    float* out = (float*)d_out;
    // ws layout: psum[NBLK] | psq[NBLK] | sem[NC]
    float*    psum = (float*)d_ws;
    float*    psq  = psum + NBLK;
    unsigned* sem  = (unsigned*)(psq + NBLK);

    hipMemsetAsync(sem, 0, NC * sizeof(unsigned), stream);

    void* args[] = { (void*)&in, (void*)&out, (void*)&psum, (void*)&psq, (void*)&sem };
    hipError_t rc = hipLaunchCooperativeKernel((const void*)instnorm_coop,
                                               dim3(NBLK), dim3(THREADS),
                                               args, 0, stream);
    if (rc != hipSuccess) {
        instnorm_partial<<<NBLK, 256, 0, stream>>>(in, psum, psq);
        const size_t total4 = (size_t)NC * HW4;
        instnorm_apply_rev<<<(int)(total4 / 256), 256, 0, stream>>>(in, out, psum, psq);
    }
}

// Round 7
// 184.159 us; speedup vs baseline: 3.9602x; 1.0539x over previous
//
#include <hip/hip_runtime.h>

#define HW_ELEMS (512 * 512)             // elements per (n,c) channel
#define HW4      (HW_ELEMS / 4)          // 65536 fx4 per channel
#define NC 192
#define THREADS 256
#define BPC 8                            // blocks per channel
#define SLICE4 (HW4 / BPC)               // 8192 fx4 per block slice (128 KB)
#define NBLK (NC * BPC)                  // 1536 blocks = 6/CU co-resident
#define EPS 1e-8f

typedef float fx4 __attribute__((ext_vector_type(4)));

// Fused instance norm with per-channel semaphore sync (no grid.sync).
// Sync-path rules learned in R6: (1) ONLY thread 0 performs coherent
// (atomic) memory ops — per-lane same-address atomic loads serialize at
// the coherence point (6.3M transactions -> 24K); (2) spin polls are
// RELAXED (acquire-per-poll emits cache invalidates); correctness comes
// from release-increment + coherent relaxed loads of the partials.
__global__ __launch_bounds__(THREADS, 6) void instnorm_coop(
    const float* __restrict__ in, float* __restrict__ out,
    float* __restrict__ psum, float* __restrict__ psq,
    unsigned* __restrict__ sem)
{
    const int s = blockIdx.x;
    const int c = s >> 3;                 // channel
    const int b = s & (BPC - 1);          // slice within channel
    const size_t base = (size_t)c * HW4 + (size_t)b * SLICE4;
    const fx4* p = reinterpret_cast<const fx4*>(in) + base;
    const int t = threadIdx.x;

    // ---- pass 1: slice stats ----
    float sum = 0.f, sq = 0.f;
#pragma unroll 8
    for (int k = 0; k < SLICE4 / THREADS; ++k) {      // 32 iters
        fx4 v = p[t + k * THREADS];
        sum += (v.x + v.y) + (v.z + v.w);
        sq  += v.x * v.x + v.y * v.y + v.z * v.z + v.w * v.w;
    }
#pragma unroll
    for (int off = 32; off > 0; off >>= 1) {
        sum += __shfl_down(sum, off, 64);
        sq  += __shfl_down(sq,  off, 64);
    }
    __shared__ float s_red[8];
    if ((t & 63) == 0) { s_red[t >> 6] = sum; s_red[4 + (t >> 6)] = sq; }
    __syncthreads();

    // ---- t0: publish partial, sync channel, combine, broadcast ----
    __shared__ float s_mean, s_rstd;
    if (t == 0) {
        float S = s_red[0] + s_red[1] + s_red[2] + s_red[3];
        float Q = s_red[4] + s_red[5] + s_red[6] + s_red[7];
        __hip_atomic_store(&psum[s], S, __ATOMIC_RELAXED, __HIP_MEMORY_SCOPE_AGENT);
        __hip_atomic_store(&psq[s],  Q, __ATOMIC_RELAXED, __HIP_MEMORY_SCOPE_AGENT);
        __hip_atomic_fetch_add(&sem[c], 1u, __ATOMIC_RELEASE, __HIP_MEMORY_SCOPE_AGENT);
        // RELAXED spin: no per-poll invalidate traffic
        while (__hip_atomic_load(&sem[c], __ATOMIC_RELAXED, __HIP_MEMORY_SCOPE_AGENT) < BPC)
            __builtin_amdgcn_s_sleep(1);
        // coherent relaxed loads see released values (publish was ordered
        // by the RELEASE increment; these loads bypass stale caches)
        float Sa = 0.f, Qa = 0.f;
#pragma unroll
        for (int i = 0; i < BPC; ++i) {
            Sa += __hip_atomic_load(&psum[c * BPC + i], __ATOMIC_RELAXED, __HIP_MEMORY_SCOPE_AGENT);
            Qa += __hip_atomic_load(&psq[c * BPC + i],  __ATOMIC_RELAXED, __HIP_MEMORY_SCOPE_AGENT);
        }
        const float n = (float)HW_ELEMS;
        float mean = Sa / n;
        float var  = (Qa - Sa * Sa / n) / (n - 1.0f);   // unbiased (ddof=1)
        if (var < 0.f) var = 0.f;
        s_mean = mean;
        s_rstd = 1.0f / (sqrtf(var) + EPS);
    }
    __syncthreads();
    const float mean = s_mean;
    const float rstd = s_rstd;

    // ---- pass 2: re-read slice (cache-hot), normalize, stream out ----
#pragma unroll 8
    for (int k = 0; k < SLICE4 / THREADS; ++k) {
        fx4 v = p[t + k * THREADS];
        fx4 r;
        r.x = (v.x - mean) * rstd;
        r.y = (v.y - mean) * rstd;
        r.z = (v.z - mean) * rstd;
        r.w = (v.w - mean) * rstd;
        __builtin_nontemporal_store(
            r, reinterpret_cast<fx4*>(out) + base + t + k * THREADS);
    }
}

// ---------- fallback path (two-kernel, R3-proven) ----------
__global__ __launch_bounds__(256) void instnorm_partial(
    const float* __restrict__ in, float* __restrict__ psum, float* __restrict__ psq)
{
    const int c = blockIdx.x >> 3;
    const int b = blockIdx.x & (BPC - 1);
    const fx4* p = reinterpret_cast<const fx4*>(in)
                 + (size_t)c * HW4 + (size_t)b * SLICE4;
    const int t = threadIdx.x;
    float sum = 0.f, sq = 0.f;
#pragma unroll 8
    for (int k = 0; k < SLICE4 / 256; ++k) {
        fx4 v = p[t + k * 256];
        sum += (v.x + v.y) + (v.z + v.w);
        sq  += v.x * v.x + v.y * v.y + v.z * v.z + v.w * v.w;
    }
#pragma unroll
    for (int off = 32; off > 0; off >>= 1) {
        sum += __shfl_down(sum, off, 64);
        sq  += __shfl_down(sq,  off, 64);
    }
    __shared__ float s_red[8];
    if ((t & 63) == 0) { s_red[t >> 6] = sum; s_red[4 + (t >> 6)] = sq; }
    __syncthreads();
    if (t == 0) {
        psum[blockIdx.x] = s_red[0] + s_red[1] + s_red[2] + s_red[3];
        psq[blockIdx.x]  = s_red[4] + s_red[5] + s_red[6] + s_red[7];
    }
}

__global__ __launch_bounds__(256) void instnorm_apply(
    const float* __restrict__ in, float* __restrict__ out,
    const float* __restrict__ psum, const float* __restrict__ psq)
{
    const int c = blockIdx.x >> 8;
    float S = 0.f, Q = 0.f;
#pragma unroll
    for (int i = 0; i < BPC; ++i) { S += psum[c * BPC + i]; Q += psq[c * BPC + i]; }
    const float n = (float)HW_ELEMS;
    float mean = S / n;
    float var  = (Q - S * S / n) / (n - 1.0f);
    if (var < 0.f) var = 0.f;
    float rstd = 1.0f / (sqrtf(var) + EPS);

    const size_t i4 = (size_t)blockIdx.x * 256 + threadIdx.x;
    fx4 v = reinterpret_cast<const fx4*>(in)[i4];
    fx4 r;
    r.x = (v.x - mean) * rstd;
    r.y = (v.y - mean) * rstd;
    r.z = (v.z - mean) * rstd;
    r.w = (v.w - mean) * rstd;
    __builtin_nontemporal_store(r, reinterpret_cast<fx4*>(out) + i4);
}

extern "C" void kernel_launch(void* const* d_in, const int* in_sizes, int n_in,
                              void* d_out, int out_size, void* d_ws, size_t ws_size,
                              hipStream_t stream) {
    const float* in = (const float*)d_in[0];
    float* out = (float*)d_out;
    // ws layout: psum[NBLK] | psq[NBLK] | sem[NC]
    float*    psum = (float*)d_ws;
    float*    psq  = psum + NBLK;
    unsigned* sem  = (unsigned*)(psq + NBLK);

    hipMemsetAsync(sem, 0, NC * sizeof(unsigned), stream);

    void* args[] = { (void*)&in, (void*)&out, (void*)&psum, (void*)&psq, (void*)&sem };
    hipError_t rc = hipLaunchCooperativeKernel((const void*)instnorm_coop,
                                               dim3(NBLK), dim3(THREADS),
                                               args, 0, stream);
    if (rc != hipSuccess) {
        instnorm_partial<<<NBLK, 256, 0, stream>>>(in, psum, psq);
        const size_t total4 = (size_t)NC * HW4;
        instnorm_apply<<<(int)(total4 / 256), 256, 0, stream>>>(in, out, psum, psq);
    }
}

// Round 8
// 138.118 us; speedup vs baseline: 5.2803x; 1.3333x over previous
//
#include <hip/hip_runtime.h>

#define HW_ELEMS (512 * 512)             // elements per (n,c) channel
#define HW4      (HW_ELEMS / 4)          // 65536 fx4 per channel
#define NC 192
#define THREADS 256
#define BPC 4                            // blocks per channel
#define SLICE4 (HW4 / BPC)               // 16384 fx4 per slice (256 KB)
#define NBLK (NC * BPC)                  // 768 blocks = 3/CU co-resident
#define EPS 1e-8f
#define BATCH 16                         // fx4 loads in flight per wave

typedef float fx4 __attribute__((ext_vector_type(4)));

// Fused instance norm, semaphore-synced (no grid.sync, no L3 re-read miss).
// R7 lesson (Little's law): the BW ceiling was in-flight bytes, not
// coherence traffic. This version buys MLP with VGPRs: BATCH=16 fx4 loads
// issued back-to-back into a register array (64 payload VGPRs) before any
// consumption. 3 blocks/CU co-residency -> VGPR cap 170, plenty.
__global__ __launch_bounds__(THREADS, 3) void instnorm_coop(
    const float* __restrict__ in, float* __restrict__ out,
    float* __restrict__ psum, float* __restrict__ psq,
    unsigned* __restrict__ sem)
{
    const int s = blockIdx.x;
    const int c = s >> 2;                 // channel  (BPC=4)
    const int b = s & (BPC - 1);          // slice within channel
    const size_t base = (size_t)c * HW4 + (size_t)b * SLICE4;
    const fx4* p = reinterpret_cast<const fx4*>(in) + base;
    const int t = threadIdx.x;

    // ---- pass 1: slice stats, 4 batches of 16 in-flight fx4 loads ----
    float sum = 0.f, sq = 0.f;
    for (int k = 0; k < SLICE4 / THREADS / BATCH; ++k) {   // 4 outer iters
        fx4 v[BATCH];
#pragma unroll
        for (int u = 0; u < BATCH; ++u)
            v[u] = p[t + (k * BATCH + u) * THREADS];
#pragma unroll
        for (int u = 0; u < BATCH; ++u) {
            sum += (v[u].x + v[u].y) + (v[u].z + v[u].w);
            sq  += v[u].x * v[u].x + v[u].y * v[u].y
                 + v[u].z * v[u].z + v[u].w * v[u].w;
        }
    }
#pragma unroll
    for (int off = 32; off > 0; off >>= 1) {
        sum += __shfl_down(sum, off, 64);
        sq  += __shfl_down(sq,  off, 64);
    }
    __shared__ float s_red[8];
    if ((t & 63) == 0) { s_red[t >> 6] = sum; s_red[4 + (t >> 6)] = sq; }
    __syncthreads();

    // ---- t0: publish partial, sync channel, combine, broadcast ----
    __shared__ float s_mean, s_rstd;
    if (t == 0) {
        float S = s_red[0] + s_red[1] + s_red[2] + s_red[3];
        float Q = s_red[4] + s_red[5] + s_red[6] + s_red[7];
        __hip_atomic_store(&psum[s], S, __ATOMIC_RELAXED, __HIP_MEMORY_SCOPE_AGENT);
        __hip_atomic_store(&psq[s],  Q, __ATOMIC_RELAXED, __HIP_MEMORY_SCOPE_AGENT);
        __hip_atomic_fetch_add(&sem[c], 1u, __ATOMIC_RELEASE, __HIP_MEMORY_SCOPE_AGENT);
        while (__hip_atomic_load(&sem[c], __ATOMIC_RELAXED, __HIP_MEMORY_SCOPE_AGENT) < BPC)
            __builtin_amdgcn_s_sleep(1);
        float Sa = 0.f, Qa = 0.f;
#pragma unroll
        for (int i = 0; i < BPC; ++i) {
            Sa += __hip_atomic_load(&psum[c * BPC + i], __ATOMIC_RELAXED, __HIP_MEMORY_SCOPE_AGENT);
            Qa += __hip_atomic_load(&psq[c * BPC + i],  __ATOMIC_RELAXED, __HIP_MEMORY_SCOPE_AGENT);
        }
        const float n = (float)HW_ELEMS;
        float mean = Sa / n;
        float var  = (Qa - Sa * Sa / n) / (n - 1.0f);   // unbiased (ddof=1)
        if (var < 0.f) var = 0.f;
        s_mean = mean;
        s_rstd = 1.0f / (sqrtf(var) + EPS);
    }
    __syncthreads();
    const float mean = s_mean;
    const float rstd = s_rstd;

    // ---- pass 2: re-read (L3-hot), normalize, nt-store; same MLP shape ----
    for (int k = 0; k < SLICE4 / THREADS / BATCH; ++k) {
        fx4 v[BATCH];
#pragma unroll
        for (int u = 0; u < BATCH; ++u)
            v[u] = p[t + (k * BATCH + u) * THREADS];
#pragma unroll
        for (int u = 0; u < BATCH; ++u) {
            fx4 r;
            r.x = (v[u].x - mean) * rstd;
            r.y = (v[u].y - mean) * rstd;
            r.z = (v[u].z - mean) * rstd;
            r.w = (v[u].w - mean) * rstd;
            __builtin_nontemporal_store(
                r, reinterpret_cast<fx4*>(out) + base + t + (k * BATCH + u) * THREADS);
        }
    }
}

// ---------- fallback path (two-kernel, R3-proven, MLP-upgraded) ----------
__global__ __launch_bounds__(256) void instnorm_partial(
    const float* __restrict__ in, float* __restrict__ psum, float* __restrict__ psq)
{
    const int c = blockIdx.x >> 2;
    const int b = blockIdx.x & (BPC - 1);
    const fx4* p = reinterpret_cast<const fx4*>(in)
                 + (size_t)c * HW4 + (size_t)b * SLICE4;
    const int t = threadIdx.x;
    float sum = 0.f, sq = 0.f;
    for (int k = 0; k < SLICE4 / 256 / BATCH; ++k) {
        fx4 v[BATCH];
#pragma unroll
        for (int u = 0; u < BATCH; ++u)
            v[u] = p[t + (k * BATCH + u) * 256];
#pragma unroll
        for (int u = 0; u < BATCH; ++u) {
            sum += (v[u].x + v[u].y) + (v[u].z + v[u].w);
            sq  += v[u].x * v[u].x + v[u].y * v[u].y
                 + v[u].z * v[u].z + v[u].w * v[u].w;
        }
    }
#pragma unroll
    for (int off = 32; off > 0; off >>= 1) {
        sum += __shfl_down(sum, off, 64);
        sq  += __shfl_down(sq,  off, 64);
    }
    __shared__ float s_red[8];
    if ((t & 63) == 0) { s_red[t >> 6] = sum; s_red[4 + (t >> 6)] = sq; }
    __syncthreads();
    if (t == 0) {
        psum[blockIdx.x] = s_red[0] + s_red[1] + s_red[2] + s_red[3];
        psq[blockIdx.x]  = s_red[4] + s_red[5] + s_red[6] + s_red[7];
    }
}

__global__ __launch_bounds__(256) void instnorm_apply(
    const float* __restrict__ in, float* __restrict__ out,
    const float* __restrict__ psum, const float* __restrict__ psq)
{
    const int c = blockIdx.x >> 8;
    float S = 0.f, Q = 0.f;
#pragma unroll
    for (int i = 0; i < BPC; ++i) { S += psum[c * BPC + i]; Q += psq[c * BPC + i]; }
    const float n = (float)HW_ELEMS;
    float mean = S / n;
    float var  = (Q - S * S / n) / (n - 1.0f);
    if (var < 0.f) var = 0.f;
    float rstd = 1.0f / (sqrtf(var) + EPS);

    const size_t i4 = (size_t)blockIdx.x * 256 + threadIdx.x;
    fx4 v = reinterpret_cast<const fx4*>(in)[i4];
    fx4 r;
    r.x = (v.x - mean) * rstd;
    r.y = (v.y - mean) * rstd;
    r.z = (v.z - mean) * rstd;
    r.w = (v.w - mean) * rstd;
    __builtin_nontemporal_store(r, reinterpret_cast<fx4*>(out) + i4);
}

extern "C" void kernel_launch(void* const* d_in, const int* in_sizes, int n_in,
                              void* d_out, int out_size, void* d_ws, size_t ws_size,
                              hipStream_t stream) {
    const float* in = (const float*)d_in[0];
    float* out = (float*)d_out;
    // ws layout: psum[NBLK] | psq[NBLK] | sem[NC]
    float*    psum = (float*)d_ws;
    float*    psq  = psum + NBLK;
    unsigned* sem  = (unsigned*)(psq + NBLK);

    hipMemsetAsync(sem, 0, NC * sizeof(unsigned), stream);

    void* args[] = { (void*)&in, (void*)&out, (void*)&psum, (void*)&psq, (void*)&sem };
    hipError_t rc = hipLaunchCooperativeKernel((const void*)instnorm_coop,
                                               dim3(NBLK), dim3(THREADS),
                                               args, 0, stream);
    if (rc != hipSuccess) {
        instnorm_partial<<<NBLK, 256, 0, stream>>>(in, psum, psq);
        const size_t total4 = (size_t)NC * HW4;
        instnorm_apply<<<(int)(total4 / 256), 256, 0, stream>>>(in, out, psum, psq);
    }
}

// Round 9
// 96.955 us; speedup vs baseline: 7.5221x; 1.4246x over previous
//
#include <hip/hip_runtime.h>

#define HW_ELEMS (512 * 512)          // elements per (n,c) channel
#define HW4      (HW_ELEMS / 4)       // 65536 fx4 per channel
#define NC 192
#define NCHUNK 3
#define CPC (NC / NCHUNK)             // 64 channels per chunk (67 MB)
#define BPC 8                         // stats blocks per channel
#define EPS 1e-8f

typedef float fx4 __attribute__((ext_vector_type(4)));

// Stats over one 64-channel chunk: 512 blocks, 256 threads, 32 fx4/thread,
// full unroll (R3-proven shape).
__global__ __launch_bounds__(256) void instnorm_partial(
    const float* __restrict__ in, float* __restrict__ psum,
    float* __restrict__ psq, int ch0)
{
    const int c = ch0 + (blockIdx.x >> 3);
    const int b = blockIdx.x & (BPC - 1);
    const fx4* p = reinterpret_cast<const fx4*>(in)
                 + (size_t)c * HW4 + (size_t)b * (HW4 / BPC);
    const int t = threadIdx.x;

    float sum = 0.f, sq = 0.f;
#pragma unroll
    for (int k = 0; k < HW4 / BPC / 256; ++k) {     // 32 iterations
        fx4 v = p[t + k * 256];
        sum += (v.x + v.y) + (v.z + v.w);
        sq  += v.x * v.x + v.y * v.y + v.z * v.z + v.w * v.w;
    }
#pragma unroll
    for (int off = 32; off > 0; off >>= 1) {
        sum += __shfl_down(sum, off, 64);
        sq  += __shfl_down(sq,  off, 64);
    }
    __shared__ float s_red[8];
    if ((t & 63) == 0) { s_red[t >> 6] = sum; s_red[4 + (t >> 6)] = sq; }
    __syncthreads();
    if (t == 0) {
        const int s = c * BPC + b;
        psum[s] = s_red[0] + s_red[1] + s_red[2] + s_red[3];
        psq[s]  = s_red[4] + s_red[5] + s_red[6] + s_red[7];
    }
}

// Apply over one chunk: fire-and-exit micro-blocks (1 fx4/thread), reads are
// L3-hot (stats for this chunk just ran), nt-store the output.
__global__ __launch_bounds__(256) void instnorm_apply(
    const float* __restrict__ in, float* __restrict__ out,
    const float* __restrict__ psum, const float* __restrict__ psq, int ch0)
{
    const size_t i4 = (size_t)ch0 * HW4 + (size_t)blockIdx.x * 256 + threadIdx.x;
    const int c = (int)(i4 >> 16);                  // 65536 fx4 per channel
    float S = 0.f, Q = 0.f;
#pragma unroll
    for (int i = 0; i < BPC; ++i) { S += psum[c * BPC + i]; Q += psq[c * BPC + i]; }
    const float n = (float)HW_ELEMS;
    float mean = S / n;
    float var  = (Q - S * S / n) / (n - 1.0f);      // unbiased (ddof=1)
    if (var < 0.f) var = 0.f;
    float rstd = 1.0f / (sqrtf(var) + EPS);

    fx4 v = reinterpret_cast<const fx4*>(in)[i4];
    fx4 r;
    r.x = (v.x - mean) * rstd;
    r.y = (v.y - mean) * rstd;
    r.z = (v.z - mean) * rstd;
    r.w = (v.w - mean) * rstd;
    __builtin_nontemporal_store(r, reinterpret_cast<fx4*>(out) + i4);
}

extern "C" void kernel_launch(void* const* d_in, const int* in_sizes, int n_in,
                              void* d_out, int out_size, void* d_ws, size_t ws_size,
                              hipStream_t stream) {
    const float* in = (const float*)d_in[0];
    float* out = (float*)d_out;
    float* psum = (float*)d_ws;          // NC*BPC floats
    float* psq  = psum + NC * BPC;

    const int statsBlk = CPC * BPC;                    // 512
    const int applyBlk = CPC * (HW4 / 256);            // 16384

    // Pipeline: S_i then A_i immediately — A_i's reads are L3-resident.
    for (int ch0 = 0; ch0 < NC; ch0 += CPC) {
        instnorm_partial<<<statsBlk, 256, 0, stream>>>(in, psum, psq, ch0);
        instnorm_apply<<<applyBlk, 256, 0, stream>>>(in, out, psum, psq, ch0);
    }
}